// Round 1
// baseline (16416.484 us; speedup 1.0000x reference)
//
#include <hip/hip_runtime.h>
#include <hip/hip_fp16.h>

// LSTM: B=128, T=1024, I=1, H=512, O=1
// Strategy: f16 MFMA recurrence, weights register-resident as B-fragments.
// Grid 256 WGs (8 batch-groups x 32 hidden-groups), per-bg atomic barrier/step.

typedef _Float16 f16;
typedef _Float16 f16x8 __attribute__((ext_vector_type(8)));
typedef float f32x4 __attribute__((ext_vector_type(4)));

#define BATCH 128
#define TT 1024
#define HID 512

// ws layout (bytes): needs ~2.26 MB
#define WPACK_OFF   0
#define WPACK_BYTES (32*4*16*64*16)          // 2 MiB packed f16 Wh fragments
#define HBUF_OFF    (WPACK_OFF + WPACK_BYTES)
#define HBUF_BYTES  (BATCH*HID*2)            // 128 KiB per buffer (x2)
#define CNT_OFF     (HBUF_OFF + 2*HBUF_BYTES)

__global__ __launch_bounds__(256) void init_kernel(float* out, const float* bl,
                                                   f16* hbuf0, unsigned int* cnt) {
    int idx = blockIdx.x * 256 + threadIdx.x;
    if (idx < BATCH * TT) out[idx] = bl[0];                 // y = bl + sum(partials)
    if (idx < BATCH * HID / 2) ((unsigned int*)hbuf0)[idx] = 0;  // h_0 = 0
    if (idx < 8) cnt[idx * 16] = 0;                         // per-bg barrier counters
}

// Pack Wh (512 x 2048, row = source hidden k, col = gate*512 + j) into per-CU
// B-fragments. Column permutation per CU slice: pcol = jj*4 + gate so each
// 16-col MFMA tile holds (i,f,g,o) quads for 4 hidden units.
__global__ __launch_bounds__(256) void pack_kernel(const float* __restrict__ Wh,
                                                   f16* __restrict__ wpack) {
    int tid  = blockIdx.x * 256 + threadIdx.x;   // 131072 = 32cg*4w*16tile*64lane
    int lane = tid & 63;
    int tile = (tid >> 6) & 15;
    int w    = (tid >> 10) & 3;
    int cg   = tid >> 12;
    int kt = tile & 3, ct = tile >> 2;
    int l_lo = lane & 15, l_hi = lane >> 4;
    int pcol = ct * 16 + l_lo;
    int jj = pcol >> 2, q = pcol & 3;
    int c = q * 512 + cg * 16 + jj;              // original Wh column
    int kbase = w * 128 + kt * 32 + l_hi * 8;
    f16x8 v;
#pragma unroll
    for (int j = 0; j < 8; ++j) v[j] = (f16)Wh[(kbase + j) * 2048 + c];
    ((f16x8*)wpack)[tid] = v;
}

__global__ __launch_bounds__(256) void lstm_kernel(
    const float* __restrict__ x, const float* __restrict__ Wx,
    const float* __restrict__ bvec, const float* __restrict__ Wl,
    const f16* __restrict__ wpack, f16* __restrict__ hbuf,
    float* __restrict__ out, unsigned int* __restrict__ cnt)
{
    const int tid = threadIdx.x;
    const int cg = blockIdx.x >> 3;      // hidden-group 0..31
    const int bg = blockIdx.x & 7;       // batch-group 0..7 (==XCD under round-robin)
    const int w = tid >> 6, lane = tid & 63;
    const int l_lo = lane & 15, l_hi = lane >> 4;

    // LDS: partial gates, layout [dest_thread(b*16+jj)][16 data + 1 pad]
    __shared__ float part[256 * 17];

    // ---- persistent B fragments: wave w owns k-slice [w*128, w*128+128) ----
    f16x8 bf[16];
    {
        const f16x8* wp = (const f16x8*)wpack + (size_t)((cg * 4 + w) * 16) * 64 + lane;
#pragma unroll
        for (int t2 = 0; t2 < 16; ++t2) bf[t2] = wp[t2 * 64];
    }

    // ---- epilogue mapping: thread owns (b_loc = tid>>4, jj = tid&15) ----
    const int b_loc = tid >> 4, jj = tid & 15;
    const int jglob = cg * 16 + jj;
    const int bglob_e = bg * 16 + b_loc;
    float bias_i = bvec[0 * 512 + jglob], bias_f = bvec[1 * 512 + jglob];
    float bias_g = bvec[2 * 512 + jglob], bias_o = bvec[3 * 512 + jglob];
    float wx_i = Wx[0 * 512 + jglob], wx_f = Wx[1 * 512 + jglob];
    float wx_g = Wx[2 * 512 + jglob], wx_o = Wx[3 * 512 + jglob];
    float wlv = Wl[jglob];
    float cst = 0.f;

    const int bglob_l = bg * 16 + l_lo;          // A-fragment batch row
    f16* hb0 = hbuf;
    f16* hb1 = hbuf + BATCH * HID;
    unsigned int* mycnt = cnt + bg * 16;

    for (int t = 0; t < TT; ++t) {
        const f16* hread = (t & 1) ? hb1 : hb0;
        f16*       hwrite = (t & 1) ? hb0 : hb1;

        // A fragments: h[bglob_l][k], k in wave's slice
        f16x8 af[4];
#pragma unroll
        for (int kt = 0; kt < 4; ++kt) {
            int k = w * 128 + kt * 32 + l_hi * 8;
            af[kt] = *(const f16x8*)(hread + bglob_l * HID + k);
        }

        f32x4 acc[4];
#pragma unroll
        for (int ct = 0; ct < 4; ++ct) acc[ct] = (f32x4){0.f, 0.f, 0.f, 0.f};
#pragma unroll
        for (int ct = 0; ct < 4; ++ct)
#pragma unroll
            for (int kt = 0; kt < 4; ++kt)
                acc[ct] = __builtin_amdgcn_mfma_f32_16x16x32_f16(
                    af[kt], bf[ct * 4 + kt], acc[ct], 0, 0, 0);

        // scatter partials to LDS: C layout col=lane&15, row=(lane>>4)*4+reg (m89)
#pragma unroll
        for (int ct = 0; ct < 4; ++ct)
#pragma unroll
            for (int r = 0; r < 4; ++r) {
                int dt = (l_hi * 4 + r) * 16 + ((ct * 16 + l_lo) >> 2);
                part[dt * 17 + w * 4 + (l_lo & 3)] = acc[ct][r];
            }
        __syncthreads();

        // gather: sum 4 wave-partials per gate
        float g[4];
#pragma unroll
        for (int q = 0; q < 4; ++q) {
            float s = 0.f;
#pragma unroll
            for (int w2 = 0; w2 < 4; ++w2) s += part[tid * 17 + w2 * 4 + q];
            g[q] = s;
        }
        float xv = x[bglob_e * TT + t];
        float gi = g[0] + xv * wx_i + bias_i;
        float gf = g[1] + xv * wx_f + bias_f;
        float gg = g[2] + xv * wx_g + bias_g;
        float go = g[3] + xv * wx_o + bias_o;
        float iv = 1.f / (1.f + __expf(-gi));
        float fv = 1.f / (1.f + __expf(-gf));
        float gv = 2.f / (1.f + __expf(-2.f * gg)) - 1.f;
        float ov = 1.f / (1.f + __expf(-go));
        cst = fv * cst + iv * gv;
        float hv = ov * (2.f / (1.f + __expf(-2.f * cst)) - 1.f);

        // readout partial: sum over this CU's 16 hidden units (lane bits 0..3)
        float p = hv * wlv;
        p += __shfl_xor(p, 1);
        p += __shfl_xor(p, 2);
        p += __shfl_xor(p, 4);
        p += __shfl_xor(p, 8);
        if ((tid & 15) == 0)
            __hip_atomic_fetch_add(&out[bglob_e * TT + t], p,
                                   __ATOMIC_RELAXED, __HIP_MEMORY_SCOPE_AGENT);

        // write h (f16) to the other buffer
        hwrite[bglob_e * HID + jglob] = (f16)hv;
        __syncthreads();   // all h stores issued; also protects LDS reuse

        if (t < TT - 1) {
            if (tid == 0) {
                __threadfence();  // release: flush h to device coherence point
                __hip_atomic_fetch_add(mycnt, 1u, __ATOMIC_RELEASE,
                                       __HIP_MEMORY_SCOPE_AGENT);
                unsigned int tgt = 32u * (unsigned)(t + 1);
                while (__hip_atomic_load(mycnt, __ATOMIC_RELAXED,
                                         __HIP_MEMORY_SCOPE_AGENT) < tgt)
                    __builtin_amdgcn_s_sleep(1);
                __threadfence();  // acquire: invalidate caches
            }
            __syncthreads();
        }
    }
}

extern "C" void kernel_launch(void* const* d_in, const int* in_sizes, int n_in,
                              void* d_out, int out_size, void* d_ws, size_t ws_size,
                              hipStream_t stream) {
    const float* x  = (const float*)d_in[0];
    const float* Wx = (const float*)d_in[1];
    const float* Wh = (const float*)d_in[2];
    const float* bv = (const float*)d_in[3];
    const float* Wl = (const float*)d_in[4];
    const float* bl = (const float*)d_in[5];
    float* out = (float*)d_out;
    char* ws = (char*)d_ws;

    f16* wpack = (f16*)(ws + WPACK_OFF);
    f16* hbuf  = (f16*)(ws + HBUF_OFF);
    unsigned int* cnt = (unsigned int*)(ws + CNT_OFF);

    init_kernel<<<512, 256, 0, stream>>>(out, bl, hbuf, cnt);
    pack_kernel<<<512, 256, 0, stream>>>(Wh, wpack);
    lstm_kernel<<<256, 256, 0, stream>>>(x, Wx, bv, Wl, wpack, hbuf, out, cnt);
}

// Round 2
// 5892.261 us; speedup vs baseline: 2.7861x; 2.7861x over previous
//
#include <hip/hip_runtime.h>
#include <hip/hip_fp16.h>

// LSTM: B=128, T=1024, I=1, H=512, O=1
// f16 MFMA recurrence, weights register-resident as B-fragments.
// Grid 256 WGs (8 batch-groups x 32 hidden-groups).
// Cross-WG h exchange via sc0/sc1 (volatile) accesses at the LLC coherence
// point -- NO cache-flushing fences (the R0 version's 2x threadfence/step
// = L2 wb/inv was 16 us/step).

typedef _Float16 f16;
typedef _Float16 f16x8 __attribute__((ext_vector_type(8)));
typedef float f32x4 __attribute__((ext_vector_type(4)));

#define BATCH 128
#define TT 1024
#define HID 512

#define WPACK_OFF   0
#define WPACK_BYTES (32*4*16*64*16)          // 2 MiB packed f16 Wh fragments
#define HBUF_OFF    (WPACK_OFF + WPACK_BYTES)
#define HBUF_BYTES  (BATCH*HID*2)            // 128 KiB per buffer (x2)
#define CNT_OFF     (HBUF_OFF + 2*HBUF_BYTES)

__global__ __launch_bounds__(256) void init_kernel(float* out, const float* bl,
                                                   f16* hbuf0, unsigned int* cnt) {
    int idx = blockIdx.x * 256 + threadIdx.x;
    if (idx < BATCH * TT) out[idx] = bl[0];                 // y = bl + sum(partials)
    if (idx < BATCH * HID / 2) ((unsigned int*)hbuf0)[idx] = 0;  // h_0 = 0
    if (idx < 8) cnt[idx * 64] = 0;                         // per-bg barrier counters
}

// Pack Wh (512 x 2048, row = source hidden k, col = gate*512 + j) into per-CU
// B-fragments. Column permutation per CU slice: pcol = jj*4 + gate so each
// 16-col MFMA tile holds (i,f,g,o) quads for 4 hidden units.
__global__ __launch_bounds__(256) void pack_kernel(const float* __restrict__ Wh,
                                                   f16* __restrict__ wpack) {
    int tid  = blockIdx.x * 256 + threadIdx.x;   // 131072 = 32cg*4w*16tile*64lane
    int lane = tid & 63;
    int tile = (tid >> 6) & 15;
    int w    = (tid >> 10) & 3;
    int cg   = tid >> 12;
    int kt = tile & 3, ct = tile >> 2;
    int l_lo = lane & 15, l_hi = lane >> 4;
    int pcol = ct * 16 + l_lo;
    int jj = pcol >> 2, q = pcol & 3;
    int c = q * 512 + cg * 16 + jj;              // original Wh column
    int kbase = w * 128 + kt * 32 + l_hi * 8;
    f16x8 v;
#pragma unroll
    for (int j = 0; j < 8; ++j) v[j] = (f16)Wh[(kbase + j) * 2048 + c];
    ((f16x8*)wpack)[tid] = v;
}

__global__ __launch_bounds__(256) void lstm_kernel(
    const float* __restrict__ x, const float* __restrict__ Wx,
    const float* __restrict__ bvec, const float* __restrict__ Wl,
    const f16* __restrict__ wpack, f16* __restrict__ hbuf,
    float* __restrict__ out, unsigned int* __restrict__ cnt)
{
    const int tid = threadIdx.x;
    const int cg = blockIdx.x >> 3;      // hidden-group 0..31
    const int bg = blockIdx.x & 7;       // batch-group 0..7 (== XCD, round-robin)
    const int w = tid >> 6, lane = tid & 63;
    const int l_lo = lane & 15, l_hi = lane >> 4;

    // LDS: partial gates, layout [dest_thread(b*16+jj)][16 data + 1 pad]
    __shared__ float part[256 * 17];

    // ---- persistent B fragments: wave w owns k-slice [w*128, w*128+128) ----
    f16x8 bf[16];
    {
        const f16x8* wp = (const f16x8*)wpack + (size_t)((cg * 4 + w) * 16) * 64 + lane;
#pragma unroll
        for (int t2 = 0; t2 < 16; ++t2) bf[t2] = wp[t2 * 64];
    }

    // ---- epilogue mapping: thread owns (b_loc = tid>>4, jj = tid&15) ----
    const int b_loc = tid >> 4, jj = tid & 15;
    const int jglob = cg * 16 + jj;
    const int bglob_e = bg * 16 + b_loc;
    float bias_i = bvec[0 * 512 + jglob], bias_f = bvec[1 * 512 + jglob];
    float bias_g = bvec[2 * 512 + jglob], bias_o = bvec[3 * 512 + jglob];
    float wx_i = Wx[0 * 512 + jglob], wx_f = Wx[1 * 512 + jglob];
    float wx_g = Wx[2 * 512 + jglob], wx_o = Wx[3 * 512 + jglob];
    float wlv = Wl[jglob];
    float cst = 0.f;

    const int bglob_l = bg * 16 + l_lo;          // A-fragment batch row
    f16* hb0 = hbuf;
    f16* hb1 = hbuf + BATCH * HID;
    unsigned int* mycnt = cnt + bg * 64;

    for (int t = 0; t < TT; ++t) {
        const f16* hread  = (t & 1) ? hb1 : hb0;
        f16*       hwrite = (t & 1) ? hb0 : hb1;

        // A fragments: h[bglob_l][k], k in wave's slice. Volatile dword loads
        // (sc0 sc1 -> bypass L1/L2, read LLC) so no acquire fence is needed.
        const volatile unsigned int* hp =
            (const volatile unsigned int*)(hread + (size_t)bglob_l * HID);
        f16x8 af[4];
#pragma unroll
        for (int kt = 0; kt < 4; ++kt) {
            int base = (w * 128 + kt * 32 + l_hi * 8) >> 1;   // uint index
            union { f16x8 v; unsigned int u[4]; } fa;
            fa.u[0] = hp[base + 0];
            fa.u[1] = hp[base + 1];
            fa.u[2] = hp[base + 2];
            fa.u[3] = hp[base + 3];
            af[kt] = fa.v;
        }

        f32x4 acc[4];
#pragma unroll
        for (int ct = 0; ct < 4; ++ct) acc[ct] = (f32x4){0.f, 0.f, 0.f, 0.f};
#pragma unroll
        for (int ct = 0; ct < 4; ++ct)
#pragma unroll
            for (int kt = 0; kt < 4; ++kt)
                acc[ct] = __builtin_amdgcn_mfma_f32_16x16x32_f16(
                    af[kt], bf[ct * 4 + kt], acc[ct], 0, 0, 0);

        // scatter partials to LDS: C layout col=lane&15, row=(lane>>4)*4+reg (m89)
#pragma unroll
        for (int ct = 0; ct < 4; ++ct)
#pragma unroll
            for (int r = 0; r < 4; ++r) {
                int dt = (l_hi * 4 + r) * 16 + ((ct * 16 + l_lo) >> 2);
                part[dt * 17 + w * 4 + (l_lo & 3)] = acc[ct][r];
            }
        __syncthreads();

        // gather: sum 4 wave-partials per gate
        float g[4];
#pragma unroll
        for (int q = 0; q < 4; ++q) {
            float s = 0.f;
#pragma unroll
            for (int w2 = 0; w2 < 4; ++w2) s += part[tid * 17 + w2 * 4 + q];
            g[q] = s;
        }
        float xv = x[bglob_e * TT + t];
        float gi = g[0] + xv * wx_i + bias_i;
        float gf = g[1] + xv * wx_f + bias_f;
        float gg = g[2] + xv * wx_g + bias_g;
        float go = g[3] + xv * wx_o + bias_o;
        float iv = 1.f / (1.f + __expf(-gi));
        float fv = 1.f / (1.f + __expf(-gf));
        float gv = 2.f / (1.f + __expf(-2.f * gg)) - 1.f;
        float ov = 1.f / (1.f + __expf(-go));
        cst = fv * cst + iv * gv;
        float hv = ov * (2.f / (1.f + __expf(-2.f * cst)) - 1.f);

        // readout partial: sum over this CU's 16 hidden units (lane bits 0..3)
        float p = hv * wlv;
        p += __shfl_xor(p, 1);
        p += __shfl_xor(p, 2);
        p += __shfl_xor(p, 4);
        p += __shfl_xor(p, 8);
        if ((tid & 15) == 0)
            __hip_atomic_fetch_add(&out[bglob_e * TT + t], p,
                                   __ATOMIC_RELAXED, __HIP_MEMORY_SCOPE_AGENT);

        // write h (f16) write-through to LLC (volatile -> sc0 sc1)
        {
            union { f16 f; unsigned short u; } cv;
            cv.f = (f16)hv;
            *(volatile unsigned short*)(hwrite + (size_t)bglob_e * HID + jglob) = cv.u;
        }

        if (t < TT - 1) {
            // Release: __syncthreads() forces per-wave s_waitcnt vmcnt(0),
            // draining every wave's write-through h stores to the coherence
            // point BEFORE thread 0's (relaxed) counter increment.
            __syncthreads();
            if (tid == 0)
                __hip_atomic_fetch_add(mycnt, 1u, __ATOMIC_RELAXED,
                                       __HIP_MEMORY_SCOPE_AGENT);
            unsigned int tgt = 32u * (unsigned)(t + 1);
            while (__hip_atomic_load(mycnt, __ATOMIC_RELAXED,
                                     __HIP_MEMORY_SCOPE_AGENT) < tgt) {}
            asm volatile("" ::: "memory");   // no compiler motion across the poll
        }
    }
}

extern "C" void kernel_launch(void* const* d_in, const int* in_sizes, int n_in,
                              void* d_out, int out_size, void* d_ws, size_t ws_size,
                              hipStream_t stream) {
    const float* x  = (const float*)d_in[0];
    const float* Wx = (const float*)d_in[1];
    const float* Wh = (const float*)d_in[2];
    const float* bv = (const float*)d_in[3];
    const float* Wl = (const float*)d_in[4];
    const float* bl = (const float*)d_in[5];
    float* out = (float*)d_out;
    char* ws = (char*)d_ws;

    f16* wpack = (f16*)(ws + WPACK_OFF);
    f16* hbuf  = (f16*)(ws + HBUF_OFF);
    unsigned int* cnt = (unsigned int*)(ws + CNT_OFF);

    init_kernel<<<512, 256, 0, stream>>>(out, bl, hbuf, cnt);
    pack_kernel<<<512, 256, 0, stream>>>(Wh, wpack);
    lstm_kernel<<<256, 256, 0, stream>>>(x, Wx, bv, Wl, wpack, hbuf, out, cnt);
}

// Round 4
// 3791.915 us; speedup vs baseline: 4.3293x; 1.5539x over previous
//
#include <hip/hip_runtime.h>
#include <hip/hip_fp16.h>

// LSTM: B=128, T=1024, I=1, H=512, O=1
// f16 MFMA recurrence, weights register-resident. 256 WGs = 8 bg x 32 cg.
// R4: R2-proven LLC protocol (sc0 sc1 + relaxed agent atomics) with:
//  - per-k-slice barrier counters (wave polls only its producer set)
//  - coalesced h layout [kblock][row][8] (dwordx4 loads)
//  - out-partials buffered 8 steps in regs, non-returning sc1 atomics post-inc
//  - LDS scatter swizzle (~2-way, free)

typedef _Float16 f16;
typedef _Float16 f16x8 __attribute__((ext_vector_type(8)));
typedef float f32x4 __attribute__((ext_vector_type(4)));

#define BATCH 128
#define TT 1024
#define HID 512

#define WPACK_OFF   0
#define WPACK_BYTES (32*4*16*64*16)              // 2 MiB packed f16 Wh fragments
#define HBUF_OFF    (WPACK_OFF + WPACK_BYTES)
#define HBUF_ELEMS  (BATCH*HID)
#define CNT_OFF     (HBUF_OFF + 2*HBUF_ELEMS*2)  // 32 counters x 128B stride

__global__ __launch_bounds__(256) void init_kernel(float* out, const float* bl,
                                                   f16* hbuf0, unsigned* cnt) {
    int idx = blockIdx.x * 256 + threadIdx.x;
    if (idx < BATCH * TT) out[idx] = bl[0];                 // y = bl + partials
    if (idx < HBUF_ELEMS / 2) ((unsigned*)hbuf0)[idx] = 0;  // h_0 = 0
    if (idx < 1024) cnt[idx] = 0;                           // (bg*4+slice)*32
}

// Pack Wh (512 x 2048, row = source hidden k, col = gate*512 + j) into per-CU
// B-fragments; column permutation pcol = jj*4 + gate (i,f,g,o quads).
__global__ __launch_bounds__(256) void pack_kernel(const float* __restrict__ Wh,
                                                   f16* __restrict__ wpack) {
    int tid  = blockIdx.x * 256 + threadIdx.x;   // 131072 = 32cg*4w*16tile*64lane
    int lane = tid & 63;
    int tile = (tid >> 6) & 15;
    int w    = (tid >> 10) & 3;
    int cg   = tid >> 12;
    int kt = tile & 3, ct = tile >> 2;
    int l_lo = lane & 15, l_hi = lane >> 4;
    int pcol = ct * 16 + l_lo;
    int jj = pcol >> 2, q = pcol & 3;
    int c = q * 512 + cg * 16 + jj;
    int kbase = w * 128 + kt * 32 + l_hi * 8;
    f16x8 v;
#pragma unroll
    for (int j = 0; j < 8; ++j) v[j] = (f16)Wh[(kbase + j) * 2048 + c];
    ((f16x8*)wpack)[tid] = v;
}

__global__ __launch_bounds__(256) void lstm_kernel(
    const float* __restrict__ x, const float* __restrict__ Wx,
    const float* __restrict__ bvec, const float* __restrict__ Wl,
    const f16* __restrict__ wpack, f16* __restrict__ hbuf,
    float* __restrict__ out, unsigned* __restrict__ cnt)
{
    const int tid = threadIdx.x;
    const int cg = blockIdx.x >> 3;      // hidden-group 0..31
    const int bg = blockIdx.x & 7;       // batch-group 0..7
    const int w = tid >> 6, lane = tid & 63;
    const int l_lo = lane & 15, l_hi = lane >> 4;

    __shared__ float part[256 * 17];

    // ---- persistent B fragments: wave w owns k-slice [w*128, w*128+128) ----
    f16x8 bf[16];
    {
        const f16x8* wp = (const f16x8*)wpack + (size_t)((cg * 4 + w) * 16) * 64 + lane;
#pragma unroll
        for (int t2 = 0; t2 < 16; ++t2) bf[t2] = wp[t2 * 64];
    }

    // ---- epilogue mapping: thread owns (b_loc = tid>>4, jj = tid&15) ----
    const int b_loc = tid >> 4, jj = tid & 15;
    const int jglob = cg * 16 + jj;
    const int bglob_e = bg * 16 + b_loc;
    float bias_i = bvec[0 * 512 + jglob], bias_f = bvec[1 * 512 + jglob];
    float bias_g = bvec[2 * 512 + jglob], bias_o = bvec[3 * 512 + jglob];
    float wx_i = Wx[0 * 512 + jglob], wx_f = Wx[1 * 512 + jglob];
    float wx_g = Wx[2 * 512 + jglob], wx_o = Wx[3 * 512 + jglob];
    float wlv = Wl[jglob];

    // h layout per bg: [kblock 64][row 16][8] f16 (8192 f16 per bg)
    const int rd_base = bg * 8192 + ((w * 16 + l_hi) * 16 + l_lo) * 8;
    const int wr_off  = bg * 8192 + ((jglob >> 3) * 16 + b_loc) * 8 + (jglob & 7);

    f16* hb0 = hbuf;
    f16* hb1 = hbuf + HBUF_ELEMS;
    // per-slice counters: slice s of bg incremented by cgs 8s..8s+7
    unsigned* cnt_inc_p        = cnt + (bg * 4 + (cg >> 3)) * 32;
    const unsigned* cnt_poll_p = cnt + (bg * 4 + w) * 32;

    float cst = 0.f;
    float pbuf[8];   // statically indexed (inner loop fully unrolled)

    for (int t8 = 0; t8 < 128; ++t8) {
#pragma unroll
        for (int u = 0; u < 8; ++u) {
            const int t = t8 * 8 + u;
            f16* hread  = (t & 1) ? hb1 : hb0;
            f16* hwrite = (t & 1) ? hb0 : hb1;

            // wait for this wave's k-slice producers (8 WGs) to finish step t-1
            if (u > 0 || t8 > 0) {
                unsigned tgt = 8u * (unsigned)t;
                while (__hip_atomic_load(cnt_poll_p, __ATOMIC_RELAXED,
                                         __HIP_MEMORY_SCOPE_AGENT) < tgt) {}
                asm volatile("" ::: "memory");
            }

            // A fragments: 4 coalesced dwordx4 from LLC (sc0 sc1)
            const f16* hp = hread + rd_base;
            f16x8 af0, af1, af2, af3;
            asm volatile("global_load_dwordx4 %0, %1, off sc0 sc1"
                         : "=v"(af0) : "v"(hp) : "memory");
            asm volatile("global_load_dwordx4 %0, %1, off sc0 sc1"
                         : "=v"(af1) : "v"(hp + 512) : "memory");
            asm volatile("global_load_dwordx4 %0, %1, off sc0 sc1"
                         : "=v"(af2) : "v"(hp + 1024) : "memory");
            asm volatile("global_load_dwordx4 %0, %1, off sc0 sc1"
                         : "=v"(af3) : "v"(hp + 1536) : "memory");
            float xv = x[bglob_e * TT + t];
            asm volatile("s_waitcnt vmcnt(0)"
                         : "+v"(af0), "+v"(af1), "+v"(af2), "+v"(af3) :: "memory");
            __builtin_amdgcn_sched_barrier(0);

            f32x4 acc[4];
#pragma unroll
            for (int ct = 0; ct < 4; ++ct) {
                f32x4 a = (f32x4){0.f, 0.f, 0.f, 0.f};
                a = __builtin_amdgcn_mfma_f32_16x16x32_f16(af0, bf[ct * 4 + 0], a, 0, 0, 0);
                a = __builtin_amdgcn_mfma_f32_16x16x32_f16(af1, bf[ct * 4 + 1], a, 0, 0, 0);
                a = __builtin_amdgcn_mfma_f32_16x16x32_f16(af2, bf[ct * 4 + 2], a, 0, 0, 0);
                a = __builtin_amdgcn_mfma_f32_16x16x32_f16(af3, bf[ct * 4 + 3], a, 0, 0, 0);
                acc[ct] = a;
            }

            // scatter partials; col rotated by (w+l_hi)&3 -> ~2-way (free)
#pragma unroll
            for (int ct = 0; ct < 4; ++ct)
#pragma unroll
                for (int r = 0; r < 4; ++r) {
                    int dt = (l_hi * 4 + r) * 16 + ((ct * 16 + l_lo) >> 2);
                    part[dt * 17 + ((w + l_hi) & 3) * 4 + (l_lo & 3)] = acc[ct][r];
                }
            __syncthreads();

            // gather: writer l_hi for dest tid is tid>>6 == w
            float g[4];
#pragma unroll
            for (int q = 0; q < 4; ++q) {
                float s = 0.f;
#pragma unroll
                for (int w2 = 0; w2 < 4; ++w2)
                    s += part[tid * 17 + ((w2 + w) & 3) * 4 + q];
                g[q] = s;
            }
            float gi = g[0] + xv * wx_i + bias_i;
            float gf = g[1] + xv * wx_f + bias_f;
            float gg = g[2] + xv * wx_g + bias_g;
            float go = g[3] + xv * wx_o + bias_o;
            float iv = 1.f / (1.f + __expf(-gi));
            float fv = 1.f / (1.f + __expf(-gf));
            float gv = 2.f / (1.f + __expf(-2.f * gg)) - 1.f;
            float ov = 1.f / (1.f + __expf(-go));
            cst = fv * cst + iv * gv;
            float hv = ov * (2.f / (1.f + __expf(-2.f * cst)) - 1.f);

            // h store issued EARLY (overlaps the shfl chain below)
            if (t < TT - 1) {
                union { f16 f; unsigned short s; } cv; cv.f = (f16)hv;
                unsigned hval = cv.s;
                asm volatile("global_store_short %0, %1, off sc0 sc1"
                             :: "v"(hwrite + wr_off), "v"(hval) : "memory");
            }

            // readout partial over this WG's 16 hidden (lane bits 0..3)
            float p = hv * wlv;
            p += __shfl_xor(p, 1);
            p += __shfl_xor(p, 2);
            p += __shfl_xor(p, 4);
            p += __shfl_xor(p, 8);
            pbuf[u] = p;

            if (t < TT - 1) {
                asm volatile("s_waitcnt vmcnt(0)" ::: "memory");  // drain h store
                __syncthreads();                                  // all waves drained
                if (tid == 0)
                    __hip_atomic_fetch_add(cnt_inc_p, 1u, __ATOMIC_RELAXED,
                                           __HIP_MEMORY_SCOPE_AGENT);
            }

            // every 8th step: fire-and-forget out atomics (LLC, sc1, no return),
            // issued after the inc so they drain inside the poll window
            if (u == 7 && (tid & 15) == 0) {
#pragma unroll
                for (int i = 0; i < 8; ++i)
                    asm volatile("global_atomic_add_f32 %0, %1, off sc1"
                                 :: "v"(out + bglob_e * TT + t8 * 8 + i),
                                    "v"(pbuf[i]) : "memory");
            }
        }
    }
}

extern "C" void kernel_launch(void* const* d_in, const int* in_sizes, int n_in,
                              void* d_out, int out_size, void* d_ws, size_t ws_size,
                              hipStream_t stream) {
    const float* x  = (const float*)d_in[0];
    const float* Wx = (const float*)d_in[1];
    const float* Wh = (const float*)d_in[2];
    const float* bv = (const float*)d_in[3];
    const float* Wl = (const float*)d_in[4];
    const float* bl = (const float*)d_in[5];
    float* out = (float*)d_out;
    char* ws = (char*)d_ws;

    f16* wpack = (f16*)(ws + WPACK_OFF);
    f16* hbuf  = (f16*)(ws + HBUF_OFF);
    unsigned* cnt = (unsigned*)(ws + CNT_OFF);

    init_kernel<<<512, 256, 0, stream>>>(out, bl, hbuf, cnt);
    pack_kernel<<<512, 256, 0, stream>>>(Wh, wpack);
    lstm_kernel<<<256, 256, 0, stream>>>(x, Wx, bv, Wl, wpack, hbuf, out, cnt);
}

// Round 5
// 2574.776 us; speedup vs baseline: 6.3759x; 1.4727x over previous
//
#include <hip/hip_runtime.h>
#include <hip/hip_fp16.h>

// LSTM: B=128, T=1024, I=1, H=512, O=1
// f16 MFMA recurrence, weights register-resident. 256 WGs = 8 bg x 32 cg.
// R5: tag-in-payload handshake. h stored as 16B chunks, each dword's bit0
// (LSB of low f16 mantissa) = step tag (t>>2)&1, 4 rotating buffers.
// Consumers poll the data directly (dwordx4 loads, check 16 tag bits) --
// no counters, no drains, no atomic RMWs on the critical path.

typedef _Float16 f16;
typedef _Float16 f16x8 __attribute__((ext_vector_type(8)));
typedef float f32x4 __attribute__((ext_vector_type(4)));

#define BATCH 128
#define TT 1024
#define HID 512

#define WPACK_OFF   0
#define WPACK_BYTES (32*4*16*64*16)              // 2 MiB packed f16 Wh fragments
#define HBUF_OFF    (WPACK_OFF + WPACK_BYTES)
#define HBUF_ELEMS  (BATCH*HID)                  // 65536 f16 = 128 KiB per buffer
// 4 buffers: HBUF_OFF .. HBUF_OFF + 4*128KiB

__global__ __launch_bounds__(256) void init_kernel(float* out, const float* bl,
                                                   unsigned* hbuf) {
    int idx = blockIdx.x * 256 + threadIdx.x;    // grid 512*256 = 131072
    if (idx < BATCH * TT) out[idx] = bl[0];      // y = bl + partials
    // 4 h buffers = 131072 dwords. buf0 = zeros (h_0, tag 0);
    // bufs 1..3 = 0x00010001 (every dword LSB=1 -> stale for tag-0 readers)
    hbuf[idx] = ((idx >> 15) == 0) ? 0u : 0x00010001u;
}

// Pack Wh (512 x 2048, row = source hidden k, col = gate*512 + j) into per-CU
// B-fragments; column permutation pcol = jj*4 + gate (i,f,g,o quads).
__global__ __launch_bounds__(256) void pack_kernel(const float* __restrict__ Wh,
                                                   f16* __restrict__ wpack) {
    int tid  = blockIdx.x * 256 + threadIdx.x;   // 131072 = 32cg*4w*16tile*64lane
    int lane = tid & 63;
    int tile = (tid >> 6) & 15;
    int w    = (tid >> 10) & 3;
    int cg   = tid >> 12;
    int kt = tile & 3, ct = tile >> 2;
    int l_lo = lane & 15, l_hi = lane >> 4;
    int pcol = ct * 16 + l_lo;
    int jj = pcol >> 2, q = pcol & 3;
    int c = q * 512 + cg * 16 + jj;
    int kbase = w * 128 + kt * 32 + l_hi * 8;
    f16x8 v;
#pragma unroll
    for (int j = 0; j < 8; ++j) v[j] = (f16)Wh[(kbase + j) * 2048 + c];
    ((f16x8*)wpack)[tid] = v;
}

__global__ __launch_bounds__(256) void lstm_kernel(
    const float* __restrict__ x, const float* __restrict__ Wx,
    const float* __restrict__ bvec, const float* __restrict__ Wl,
    const f16* __restrict__ wpack, f16* __restrict__ hbuf,
    float* __restrict__ out)
{
    const int tid = threadIdx.x;
    const int cg = blockIdx.x >> 3;      // hidden-group 0..31
    const int bg = blockIdx.x & 7;       // batch-group 0..7
    const int w = tid >> 6, lane = tid & 63;
    const int l_lo = lane & 15, l_hi = lane >> 4;

    __shared__ float part[256 * 17];
    __shared__ f16 hstage[256];          // [row 16][jj 16]

    // ---- persistent B fragments: wave w owns k-slice [w*128, w*128+128) ----
    f16x8 bf[16];
    {
        const f16x8* wp = (const f16x8*)wpack + (size_t)((cg * 4 + w) * 16) * 64 + lane;
#pragma unroll
        for (int t2 = 0; t2 < 16; ++t2) bf[t2] = wp[t2 * 64];
    }

    // ---- epilogue mapping: thread owns (b_loc = tid>>4, jj = tid&15) ----
    const int b_loc = tid >> 4, jj = tid & 15;
    const int jglob = cg * 16 + jj;
    const int bglob_e = bg * 16 + b_loc;
    float bias_i = bvec[0 * 512 + jglob], bias_f = bvec[1 * 512 + jglob];
    float bias_g = bvec[2 * 512 + jglob], bias_o = bvec[3 * 512 + jglob];
    float wx_i = Wx[0 * 512 + jglob], wx_f = Wx[1 * 512 + jglob];
    float wx_g = Wx[2 * 512 + jglob], wx_o = Wx[3 * 512 + jglob];
    float wlv = Wl[jglob];

    // h layout per bg: [kblock 64][row 16][8] f16 (8192 f16 per bg).
    // consumer: kblock = w*16 + l_hi + kt*4, row = l_lo
    const int rd_base = bg * 8192 + ((w * 16 + l_hi) * 16 + l_lo) * 8;
    // producer storer role (tid<32): chunk (row = tid>>1, kb = tid&1)
    const int srow = tid >> 1, skb = tid & 1;
    const int st_off = bg * 8192 + (((cg * 2 + skb) * 16 + srow) * 8);

    float cst = 0.f;
    float pbuf[8];   // statically indexed (inner loop fully unrolled)

    for (int t8 = 0; t8 < 128; ++t8) {
#pragma unroll
        for (int u = 0; u < 8; ++u) {
            const int t = t8 * 8 + u;
            const f16* hp = hbuf + (size_t)(t & 3) * HBUF_ELEMS + rd_base;
            const unsigned expect = (unsigned)((t >> 2) & 1);

            // ---- poll the data itself: retry until all 16 dword tags fresh ----
            f16x8 af0, af1, af2, af3;
            for (;;) {
                asm volatile(
                    "global_load_dwordx4 %0, %4, off sc0 sc1\n\t"
                    "global_load_dwordx4 %1, %5, off sc0 sc1\n\t"
                    "global_load_dwordx4 %2, %6, off sc0 sc1\n\t"
                    "global_load_dwordx4 %3, %7, off sc0 sc1\n\t"
                    "s_waitcnt vmcnt(0)"
                    : "=&v"(af0), "=&v"(af1), "=&v"(af2), "=&v"(af3)
                    : "v"(hp), "v"(hp + 512), "v"(hp + 1024), "v"(hp + 1536)
                    : "memory");
                union { f16x8 v; unsigned u4[4]; } a0, a1, a2, a3;
                a0.v = af0; a1.v = af1; a2.v = af2; a3.v = af3;
                unsigned d0 = a0.u4[0] ^ a0.u4[1] ^ 0u; // tag check: every dword
                unsigned m0 = (a0.u4[0] | a0.u4[1] | a0.u4[2] | a0.u4[3]) &
                              (a0.u4[0] & a0.u4[1] & a0.u4[2] & a0.u4[3]);
                (void)d0; (void)m0;
                unsigned bad =
                    (((a0.u4[0] ^ expect) | (a0.u4[1] ^ expect) |
                      (a0.u4[2] ^ expect) | (a0.u4[3] ^ expect)) |
                     ((a1.u4[0] ^ expect) | (a1.u4[1] ^ expect) |
                      (a1.u4[2] ^ expect) | (a1.u4[3] ^ expect)) |
                     ((a2.u4[0] ^ expect) | (a2.u4[1] ^ expect) |
                      (a2.u4[2] ^ expect) | (a2.u4[3] ^ expect)) |
                     ((a3.u4[0] ^ expect) | (a3.u4[1] ^ expect) |
                      (a3.u4[2] ^ expect) | (a3.u4[3] ^ expect))) & 1u;
                if (__all(bad == 0u)) break;
            }
            __builtin_amdgcn_sched_barrier(0);

            float xv = x[bglob_e * TT + t];

            f32x4 acc[4];
#pragma unroll
            for (int ct = 0; ct < 4; ++ct) {
                f32x4 a = (f32x4){0.f, 0.f, 0.f, 0.f};
                a = __builtin_amdgcn_mfma_f32_16x16x32_f16(af0, bf[ct * 4 + 0], a, 0, 0, 0);
                a = __builtin_amdgcn_mfma_f32_16x16x32_f16(af1, bf[ct * 4 + 1], a, 0, 0, 0);
                a = __builtin_amdgcn_mfma_f32_16x16x32_f16(af2, bf[ct * 4 + 2], a, 0, 0, 0);
                a = __builtin_amdgcn_mfma_f32_16x16x32_f16(af3, bf[ct * 4 + 3], a, 0, 0, 0);
                acc[ct] = a;
            }

            // scatter partials; col rotated by (w+l_hi)&3 -> ~2-way (free)
#pragma unroll
            for (int ct = 0; ct < 4; ++ct)
#pragma unroll
                for (int r = 0; r < 4; ++r) {
                    int dt = (l_hi * 4 + r) * 16 + ((ct * 16 + l_lo) >> 2);
                    part[dt * 17 + ((w + l_hi) & 3) * 4 + (l_lo & 3)] = acc[ct][r];
                }
            __syncthreads();

            // gather: writer group for dest tid is w
            float g[4];
#pragma unroll
            for (int q = 0; q < 4; ++q) {
                float s = 0.f;
#pragma unroll
                for (int w2 = 0; w2 < 4; ++w2)
                    s += part[tid * 17 + ((w2 + w) & 3) * 4 + q];
                g[q] = s;
            }
            float gi = g[0] + xv * wx_i + bias_i;
            float gf = g[1] + xv * wx_f + bias_f;
            float gg = g[2] + xv * wx_g + bias_g;
            float go = g[3] + xv * wx_o + bias_o;
            float iv = 1.f / (1.f + __expf(-gi));
            float fv = 1.f / (1.f + __expf(-gf));
            float gv = 2.f / (1.f + __expf(-2.f * gg)) - 1.f;
            float ov = 1.f / (1.f + __expf(-go));
            cst = fv * cst + iv * gv;
            float hv = ov * (2.f / (1.f + __expf(-2.f * cst)) - 1.f);

            // stage h through LDS so storers can emit whole 16B tagged chunks
            {
                union { f16 f; unsigned short s; } cv; cv.f = (f16)hv;
                hstage[b_loc * 16 + jj] = cv.f;
                (void)cv;
            }

            // readout partial over this WG's 16 hidden (lane bits 0..3)
            float p = hv * wlv;
            p += __shfl_xor(p, 1);
            p += __shfl_xor(p, 2);
            p += __shfl_xor(p, 4);
            p += __shfl_xor(p, 8);
            pbuf[u] = p;

            __syncthreads();

            // storers: pack 8 f16, force per-dword tag LSB, fire-and-forget
            if (tid < 32 && t < TT - 1) {
                const unsigned wtag = (unsigned)(((t + 1) >> 2) & 1);
                const unsigned* src = (const unsigned*)(hstage + srow * 16 + skb * 8);
                union { unsigned u4[4]; f16x8 v; } pk;
#pragma unroll
                for (int i = 0; i < 4; ++i)
                    pk.u4[i] = (src[i] & ~1u) | wtag;
                f16* dst = hbuf + (size_t)((t + 1) & 3) * HBUF_ELEMS + st_off;
                asm volatile("global_store_dwordx4 %0, %1, off sc0 sc1"
                             :: "v"(dst), "v"(pk.v) : "memory");
            }

            // every 8th step: fire-and-forget out atomics (LLC, off-path)
            if (u == 7 && (tid & 15) == 0) {
#pragma unroll
                for (int i = 0; i < 8; ++i)
                    asm volatile("global_atomic_add_f32 %0, %1, off sc1"
                                 :: "v"(out + bglob_e * TT + t8 * 8 + i),
                                    "v"(pbuf[i]) : "memory");
            }
        }
    }
}

extern "C" void kernel_launch(void* const* d_in, const int* in_sizes, int n_in,
                              void* d_out, int out_size, void* d_ws, size_t ws_size,
                              hipStream_t stream) {
    const float* x  = (const float*)d_in[0];
    const float* Wx = (const float*)d_in[1];
    const float* Wh = (const float*)d_in[2];
    const float* bv = (const float*)d_in[3];
    const float* Wl = (const float*)d_in[4];
    const float* bl = (const float*)d_in[5];
    float* out = (float*)d_out;
    char* ws = (char*)d_ws;

    f16* wpack = (f16*)(ws + WPACK_OFF);
    f16* hbuf  = (f16*)(ws + HBUF_OFF);

    init_kernel<<<512, 256, 0, stream>>>(out, bl, (unsigned*)hbuf);
    pack_kernel<<<512, 256, 0, stream>>>(Wh, wpack);
    lstm_kernel<<<256, 256, 0, stream>>>(x, Wx, bv, Wl, wpack, hbuf, out);
}

// Round 6
// 2440.671 us; speedup vs baseline: 6.7262x; 1.0549x over previous
//
#include <hip/hip_runtime.h>
#include <hip/hip_fp16.h>

// LSTM: B=128, T=1024, I=1, H=512, O=1
// f16 MFMA recurrence, weights register-resident. 256 WGs = 8 bg x 32 cg.
// R6: tag-in-payload protocol (R5) + per-wave shuffle-pack publish (no LDS
// stage, no 2nd barrier -- each wave publishes its 4 rows immediately),
// double-buffered LDS partials, x prefetched 8 steps at a time.

typedef _Float16 f16;
typedef _Float16 f16x8 __attribute__((ext_vector_type(8)));
typedef float f32x4 __attribute__((ext_vector_type(4)));

#define BATCH 128
#define TT 1024
#define HID 512

#define WPACK_OFF   0
#define WPACK_BYTES (32*4*16*64*16)              // 2 MiB packed f16 Wh fragments
#define HBUF_OFF    (WPACK_OFF + WPACK_BYTES)
#define HBUF_ELEMS  (BATCH*HID)                  // 65536 f16 = 128 KiB per buffer
// 4 rotating buffers follow HBUF_OFF

__global__ __launch_bounds__(256) void init_kernel(float* out, const float* bl,
                                                   unsigned* hbuf) {
    int idx = blockIdx.x * 256 + threadIdx.x;    // grid 512*256 = 131072
    if (idx < BATCH * TT) out[idx] = bl[0];      // y = bl + partials
    // 4 h buffers = 131072 dwords. buf0 = zeros (h_0, tag 0);
    // bufs 1..3 = 0x00010001 (dword LSB=1 -> stale for tag-0 readers)
    hbuf[idx] = ((idx >> 15) == 0) ? 0u : 0x00010001u;
}

// Pack Wh (512 x 2048, row = source hidden k, col = gate*512 + j) into per-CU
// B-fragments; column permutation pcol = jj*4 + gate (i,f,g,o quads).
__global__ __launch_bounds__(256) void pack_kernel(const float* __restrict__ Wh,
                                                   f16* __restrict__ wpack) {
    int tid  = blockIdx.x * 256 + threadIdx.x;   // 131072 = 32cg*4w*16tile*64lane
    int lane = tid & 63;
    int tile = (tid >> 6) & 15;
    int w    = (tid >> 10) & 3;
    int cg   = tid >> 12;
    int kt = tile & 3, ct = tile >> 2;
    int l_lo = lane & 15, l_hi = lane >> 4;
    int pcol = ct * 16 + l_lo;
    int jj = pcol >> 2, q = pcol & 3;
    int c = q * 512 + cg * 16 + jj;
    int kbase = w * 128 + kt * 32 + l_hi * 8;
    f16x8 v;
#pragma unroll
    for (int j = 0; j < 8; ++j) v[j] = (f16)Wh[(kbase + j) * 2048 + c];
    ((f16x8*)wpack)[tid] = v;
}

__global__ __launch_bounds__(256) void lstm_kernel(
    const float* __restrict__ x, const float* __restrict__ Wx,
    const float* __restrict__ bvec, const float* __restrict__ Wl,
    const f16* __restrict__ wpack, f16* __restrict__ hbuf,
    float* __restrict__ out)
{
    const int tid = threadIdx.x;
    const int cg = blockIdx.x >> 3;      // hidden-group 0..31
    const int bg = blockIdx.x & 7;       // batch-group 0..7
    const int w = tid >> 6, lane = tid & 63;
    const int l_lo = lane & 15, l_hi = lane >> 4;

    __shared__ float part[2][256 * 17];  // double-buffered (one barrier/step)

    // ---- persistent B fragments: wave w owns k-slice [w*128, w*128+128) ----
    f16x8 bf[16];
    {
        const f16x8* wp = (const f16x8*)wpack + (size_t)((cg * 4 + w) * 16) * 64 + lane;
#pragma unroll
        for (int t2 = 0; t2 < 16; ++t2) bf[t2] = wp[t2 * 64];
    }

    // ---- epilogue mapping: thread owns (b_loc = tid>>4, jj = tid&15) ----
    const int b_loc = tid >> 4, jj = tid & 15;
    const int jglob = cg * 16 + jj;
    const int bglob_e = bg * 16 + b_loc;
    float bias_i = bvec[0 * 512 + jglob], bias_f = bvec[1 * 512 + jglob];
    float bias_g = bvec[2 * 512 + jglob], bias_o = bvec[3 * 512 + jglob];
    float wx_i = Wx[0 * 512 + jglob], wx_f = Wx[1 * 512 + jglob];
    float wx_g = Wx[2 * 512 + jglob], wx_o = Wx[3 * 512 + jglob];
    float wlv = Wl[jglob];

    // h layout per bg: [kblock 64][row 16][8] f16 (8192 f16 per bg).
    const int rd_base = bg * 8192 + ((w * 16 + l_hi) * 16 + l_lo) * 8;
    // per-wave publish: storer lane L<8 handles (row = 4w + (L>>1), chunk q=L&1)
    const int Lr = (lane >> 1) & 3, q = lane & 1;
    const int st_off = bg * 8192 + (((cg * 2 + q) * 16) + 4 * w + Lr) * 8;

    float cst = 0.f;
    float pbuf[8];   // statically indexed (inner loop fully unrolled)

    for (int t8 = 0; t8 < 128; ++t8) {
        // prefetch 8 steps of x (cached loads, off critical path)
        float xbuf[8];
        {
            const float4* xp = (const float4*)(x + (size_t)bglob_e * TT + t8 * 8);
            float4 xa = xp[0], xb = xp[1];
            xbuf[0] = xa.x; xbuf[1] = xa.y; xbuf[2] = xa.z; xbuf[3] = xa.w;
            xbuf[4] = xb.x; xbuf[5] = xb.y; xbuf[6] = xb.z; xbuf[7] = xb.w;
        }
#pragma unroll
        for (int u = 0; u < 8; ++u) {
            const int t = t8 * 8 + u;
            const f16* hp = hbuf + (size_t)(t & 3) * HBUF_ELEMS + rd_base;
            const unsigned expect = (unsigned)((t >> 2) & 1);

            // ---- poll the data itself: retry until all 16 dword tags fresh ----
            f16x8 af0, af1, af2, af3;
            for (;;) {
                asm volatile(
                    "global_load_dwordx4 %0, %4, off sc0 sc1\n\t"
                    "global_load_dwordx4 %1, %5, off sc0 sc1\n\t"
                    "global_load_dwordx4 %2, %6, off sc0 sc1\n\t"
                    "global_load_dwordx4 %3, %7, off sc0 sc1\n\t"
                    "s_waitcnt vmcnt(0)"
                    : "=&v"(af0), "=&v"(af1), "=&v"(af2), "=&v"(af3)
                    : "v"(hp), "v"(hp + 512), "v"(hp + 1024), "v"(hp + 1536)
                    : "memory");
                union { f16x8 v; unsigned u4[4]; } a0, a1, a2, a3;
                a0.v = af0; a1.v = af1; a2.v = af2; a3.v = af3;
                unsigned bad =
                    (((a0.u4[0] ^ expect) | (a0.u4[1] ^ expect) |
                      (a0.u4[2] ^ expect) | (a0.u4[3] ^ expect)) |
                     ((a1.u4[0] ^ expect) | (a1.u4[1] ^ expect) |
                      (a1.u4[2] ^ expect) | (a1.u4[3] ^ expect)) |
                     ((a2.u4[0] ^ expect) | (a2.u4[1] ^ expect) |
                      (a2.u4[2] ^ expect) | (a2.u4[3] ^ expect)) |
                     ((a3.u4[0] ^ expect) | (a3.u4[1] ^ expect) |
                      (a3.u4[2] ^ expect) | (a3.u4[3] ^ expect))) & 1u;
                if (__all(bad == 0u)) break;
            }
            __builtin_amdgcn_sched_barrier(0);

            f32x4 acc[4];
#pragma unroll
            for (int ct = 0; ct < 4; ++ct) {
                f32x4 a = (f32x4){0.f, 0.f, 0.f, 0.f};
                a = __builtin_amdgcn_mfma_f32_16x16x32_f16(af0, bf[ct * 4 + 0], a, 0, 0, 0);
                a = __builtin_amdgcn_mfma_f32_16x16x32_f16(af1, bf[ct * 4 + 1], a, 0, 0, 0);
                a = __builtin_amdgcn_mfma_f32_16x16x32_f16(af2, bf[ct * 4 + 2], a, 0, 0, 0);
                a = __builtin_amdgcn_mfma_f32_16x16x32_f16(af3, bf[ct * 4 + 3], a, 0, 0, 0);
                acc[ct] = a;
            }

            // scatter partials; col rotated by (w+l_hi)&3 -> ~2-way (free)
            float* pb = part[t & 1];
#pragma unroll
            for (int ct = 0; ct < 4; ++ct)
#pragma unroll
                for (int r = 0; r < 4; ++r) {
                    int dt = (l_hi * 4 + r) * 16 + ((ct * 16 + l_lo) >> 2);
                    pb[dt * 17 + ((w + l_hi) & 3) * 4 + (l_lo & 3)] = acc[ct][r];
                }
            __syncthreads();

            // gather: writer group for dest tid is w
            float g[4];
#pragma unroll
            for (int qq = 0; qq < 4; ++qq) {
                float s = 0.f;
#pragma unroll
                for (int w2 = 0; w2 < 4; ++w2)
                    s += pb[tid * 17 + ((w2 + w) & 3) * 4 + qq];
                g[qq] = s;
            }
            float xv = xbuf[u];
            float gi = g[0] + xv * wx_i + bias_i;
            float gf = g[1] + xv * wx_f + bias_f;
            float gg = g[2] + xv * wx_g + bias_g;
            float go = g[3] + xv * wx_o + bias_o;
            float iv = 1.f / (1.f + __expf(-gi));
            float fv = 1.f / (1.f + __expf(-gf));
            float gv = 2.f / (1.f + __expf(-2.f * gg)) - 1.f;
            float ov = 1.f / (1.f + __expf(-go));
            cst = fv * cst + iv * gv;
            float hv = ov * (2.f / (1.f + __expf(-2.f * cst)) - 1.f);

            // ---- per-wave publish: shuffle-pack this wave's 4 rows ----
            unsigned hval;
            { union { f16 f; unsigned short s; } cv; cv.f = (f16)hv; hval = cv.s; }
            // source lane for element e of chunk (Lr, q): Lr*16 + q*8 + e
            unsigned s0 = __shfl(hval, Lr * 16 + q * 8 + 0);
            unsigned s1 = __shfl(hval, Lr * 16 + q * 8 + 1);
            unsigned s2 = __shfl(hval, Lr * 16 + q * 8 + 2);
            unsigned s3 = __shfl(hval, Lr * 16 + q * 8 + 3);
            unsigned s4 = __shfl(hval, Lr * 16 + q * 8 + 4);
            unsigned s5 = __shfl(hval, Lr * 16 + q * 8 + 5);
            unsigned s6 = __shfl(hval, Lr * 16 + q * 8 + 6);
            unsigned s7 = __shfl(hval, Lr * 16 + q * 8 + 7);
            if (lane < 8 && t < TT - 1) {
                const unsigned wtag = (unsigned)(((t + 1) >> 2) & 1);
                union { unsigned u4[4]; f16x8 v; } pk;
                pk.u4[0] = ((s0 | (s1 << 16)) & ~1u) | wtag;
                pk.u4[1] = ((s2 | (s3 << 16)) & ~1u) | wtag;
                pk.u4[2] = ((s4 | (s5 << 16)) & ~1u) | wtag;
                pk.u4[3] = ((s6 | (s7 << 16)) & ~1u) | wtag;
                f16* dst = hbuf + (size_t)((t + 1) & 3) * HBUF_ELEMS + st_off;
                asm volatile("global_store_dwordx4 %0, %1, off sc0 sc1"
                             :: "v"(dst), "v"(pk.v) : "memory");
            }

            // readout partial over this WG's 16 hidden (lane bits 0..3)
            float p = hv * wlv;
            p += __shfl_xor(p, 1);
            p += __shfl_xor(p, 2);
            p += __shfl_xor(p, 4);
            p += __shfl_xor(p, 8);
            pbuf[u] = p;

            // every 8th step: fire-and-forget out atomics (LLC, off-path)
            if (u == 7 && (tid & 15) == 0) {
#pragma unroll
                for (int i = 0; i < 8; ++i)
                    asm volatile("global_atomic_add_f32 %0, %1, off sc1"
                                 :: "v"(out + bglob_e * TT + t8 * 8 + i),
                                    "v"(pbuf[i]) : "memory");
            }
        }
    }
}

extern "C" void kernel_launch(void* const* d_in, const int* in_sizes, int n_in,
                              void* d_out, int out_size, void* d_ws, size_t ws_size,
                              hipStream_t stream) {
    const float* x  = (const float*)d_in[0];
    const float* Wx = (const float*)d_in[1];
    const float* Wh = (const float*)d_in[2];
    const float* bv = (const float*)d_in[3];
    const float* Wl = (const float*)d_in[4];
    const float* bl = (const float*)d_in[5];
    float* out = (float*)d_out;
    char* ws = (char*)d_ws;

    f16* wpack = (f16*)(ws + WPACK_OFF);
    f16* hbuf  = (f16*)(ws + HBUF_OFF);

    init_kernel<<<512, 256, 0, stream>>>(out, bl, (unsigned*)hbuf);
    pack_kernel<<<512, 256, 0, stream>>>(Wh, wpack);
    lstm_kernel<<<256, 256, 0, stream>>>(x, Wx, bv, Wl, wpack, hbuf, out);
}

// Round 7
// 2346.009 us; speedup vs baseline: 6.9976x; 1.0404x over previous
//
#include <hip/hip_runtime.h>
#include <hip/hip_fp16.h>

// LSTM: B=128, T=1024, I=1, H=512, O=1
// R7: tag-in-payload protocol (proven R5/R6) with re-partition:
//   poll k-slice per wave -> LDS full-h tile (XOR-swizzled, dbuf, 1 barrier)
//   -> each wave computes its 16 cols over FULL k (16 MFMAs, no cross-wave sum)
//   -> in-wave 4x4 shfl transpose -> act -> tagged publish.
// Readout y = bl + h@Wl done by designated waves in post-publish slack from
// register-resident af (single writer, plain stores, no atomics, no out init).

typedef _Float16 f16;
typedef _Float16 f16x8 __attribute__((ext_vector_type(8)));
typedef float f32x4 __attribute__((ext_vector_type(4)));

#define BATCH 128
#define TT 1024
#define HID 512

#define WPACK_OFF   0
#define WPACK_BYTES (32*4*16*64*16)              // 2 MiB packed f16 Wh fragments
#define HBUF_OFF    (WPACK_OFF + WPACK_BYTES)
#define HBUF_ELEMS  (BATCH*HID)                  // 65536 f16 = 128 KiB per buffer
#define WL16_OFF    (HBUF_OFF + 4*HBUF_ELEMS*2)  // 512 f16 Wl

__global__ __launch_bounds__(256) void init_kernel(const float* Wl, f16* wl16,
                                                   unsigned* hbuf) {
    int idx = blockIdx.x * 256 + threadIdx.x;    // grid 512*256 = 131072
    // 4 h buffers = 131072 dwords. buf0 = zeros (h_0, tag 0);
    // bufs 1..3 = 0x00010001 (dword bit0=1 -> stale for tag-0 readers)
    hbuf[idx] = ((idx >> 15) == 0) ? 0u : 0x00010001u;
    if (idx < HID) wl16[idx] = (f16)Wl[idx];
}

// Pack Wh (512 x 2048, row = source k, col = gate*512 + j) into per-(cg,wave)
// B-fragments covering FULL k: tile j (k = j*32), 16-col slice of wave wv.
// pcol = jj*4 + q maps (unit jj 0..3, gate q) -> c = q*512 + cg*16 + wv*4 + jj.
__global__ __launch_bounds__(256) void pack_kernel(const float* __restrict__ Wh,
                                                   f16* __restrict__ wpack) {
    int tid  = blockIdx.x * 256 + threadIdx.x;   // 131072 = 32cg*4wv*16j*64lane
    int lane = tid & 63;
    int j    = (tid >> 6) & 15;
    int wv   = (tid >> 10) & 3;
    int cg   = tid >> 12;
    int l_lo = lane & 15, l_hi = lane >> 4;
    int jj = l_lo >> 2, q = l_lo & 3;
    int c = q * 512 + cg * 16 + wv * 4 + jj;
    int kbase = j * 32 + l_hi * 8;
    f16x8 v;
#pragma unroll
    for (int e = 0; e < 8; ++e) v[e] = (f16)Wh[(kbase + e) * 2048 + c];
    ((f16x8*)wpack)[tid] = v;
}

__global__ __launch_bounds__(256, 1) void lstm_kernel(
    const float* __restrict__ x, const float* __restrict__ Wx,
    const float* __restrict__ bvec, const float* __restrict__ blp,
    const f16* __restrict__ wpack, f16* __restrict__ hbuf,
    const f16* __restrict__ wl16, float* __restrict__ out)
{
    const int tid = threadIdx.x;
    const int cg = blockIdx.x >> 3;      // hidden-group 0..31
    const int bg = blockIdx.x & 7;       // batch-group 0..7
    const int w = tid >> 6, lane = tid & 63;
    const int l_lo = lane & 15, l_hi = lane >> 4;

    __shared__ f16 hsh[2][8192];         // [row16][k512], XOR-swizzled, dbuf
    __shared__ f16 wlsh[512];

    if (tid < 64)                         // Wl -> LDS once
        *(f16x8*)(wlsh + tid * 8) = *(const f16x8*)(wl16 + tid * 8);

    // ---- persistent B fragments: full k, wave's 16-col slice ----
    f16x8 bf[16];
    {
        const f16x8* wp = (const f16x8*)wpack + (size_t)((cg * 4 + w) * 16) * 64 + lane;
#pragma unroll
        for (int j = 0; j < 16; ++j) bf[j] = wp[j * 64];
    }

    // ---- per-lane (row, unit) ownership after transpose ----
    const int row  = l_hi * 4 + (l_lo & 3);
    const int uglob = cg * 16 + w * 4 + (l_lo >> 2);
    const int bglob = bg * 16 + row;
    const float bias_i = bvec[0*512+uglob], bias_f = bvec[1*512+uglob];
    const float bias_g = bvec[2*512+uglob], bias_o = bvec[3*512+uglob];
    const float wx_i = Wx[0*512+uglob], wx_f = Wx[1*512+uglob];
    const float wx_g = Wx[2*512+uglob], wx_o = Wx[3*512+uglob];
    const float blv = blp[0];

    // poll: lane covers row l_lo, k in wave w's quarter (same as R6)
    const int rd_base = bg * 8192 + ((w * 16 + l_hi) * 16 + l_lo) * 8;
    // publish (even-unit lanes): chunk [kblock=uglob>>3][row][f16 uglob&7]
    const int st_idx = bg * 8192 + ((uglob >> 3) * 16 + row) * 8 + (uglob & 7);

    const int p4 = l_lo & 3;             // in-group transpose id
#define SWZ(b) ((b) ^ ((l_lo & 7) << 4))

    float cst = 0.f;

    for (int t = 0; t <= TT; ++t) {
        const f16* hp = hbuf + (size_t)(t & 3) * HBUF_ELEMS + rd_base;
        const unsigned expect = (unsigned)((t >> 2) & 1);

        // ---- poll the data itself: all 16 dword tags must be fresh ----
        f16x8 s0, s1, s2, s3;
        for (;;) {
            asm volatile(
                "global_load_dwordx4 %0, %4, off sc0 sc1\n\t"
                "global_load_dwordx4 %1, %5, off sc0 sc1\n\t"
                "global_load_dwordx4 %2, %6, off sc0 sc1\n\t"
                "global_load_dwordx4 %3, %7, off sc0 sc1\n\t"
                "s_waitcnt vmcnt(0)"
                : "=&v"(s0), "=&v"(s1), "=&v"(s2), "=&v"(s3)
                : "v"(hp), "v"(hp + 512), "v"(hp + 1024), "v"(hp + 1536)
                : "memory");
            union { f16x8 v; unsigned u[4]; } a0, a1, a2, a3;
            a0.v = s0; a1.v = s1; a2.v = s2; a3.v = s3;
            unsigned bad =
                ((a0.u[0] ^ expect) | (a0.u[1] ^ expect) |
                 (a0.u[2] ^ expect) | (a0.u[3] ^ expect) |
                 (a1.u[0] ^ expect) | (a1.u[1] ^ expect) |
                 (a1.u[2] ^ expect) | (a1.u[3] ^ expect) |
                 (a2.u[0] ^ expect) | (a2.u[1] ^ expect) |
                 (a2.u[2] ^ expect) | (a2.u[3] ^ expect) |
                 (a3.u[0] ^ expect) | (a3.u[1] ^ expect) |
                 (a3.u[2] ^ expect) | (a3.u[3] ^ expect)) & 1u;
            if (__all(bad == 0u)) break;
        }
        __builtin_amdgcn_sched_barrier(0);

        // ---- stage wave's k-quarter into shared h tile (swizzled) ----
        char* hb = (char*)hsh[t & 1];
        const int wb = l_lo * 1024 + w * 256 + l_hi * 16;
        *(f16x8*)(hb + SWZ(wb +   0)) = s0;
        *(f16x8*)(hb + SWZ(wb +  64)) = s1;
        *(f16x8*)(hb + SWZ(wb + 128)) = s2;
        *(f16x8*)(hb + SWZ(wb + 192)) = s3;
        __syncthreads();

        // ---- full-k A fragments from LDS ----
        f16x8 af[16];
#pragma unroll
        for (int j = 0; j < 16; ++j)
            af[j] = *(const f16x8*)(hb + SWZ(l_lo * 1024 + j * 64 + l_hi * 16));

        if (t < TT) {
            float xv = x[bglob * TT + t];

            // 16 MFMAs, 4 independent chains, then tree-sum
            f32x4 a0 = {0,0,0,0}, a1 = {0,0,0,0}, a2 = {0,0,0,0}, a3 = {0,0,0,0};
#pragma unroll
            for (int i = 0; i < 4; ++i) {
                a0 = __builtin_amdgcn_mfma_f32_16x16x32_f16(af[ 0+i], bf[ 0+i], a0, 0,0,0);
                a1 = __builtin_amdgcn_mfma_f32_16x16x32_f16(af[ 4+i], bf[ 4+i], a1, 0,0,0);
                a2 = __builtin_amdgcn_mfma_f32_16x16x32_f16(af[ 8+i], bf[ 8+i], a2, 0,0,0);
                a3 = __builtin_amdgcn_mfma_f32_16x16x32_f16(af[12+i], bf[12+i], a3, 0,0,0);
            }
            f32x4 m = (a0 + a1) + (a2 + a3);
            // m[r] = gates(pcol=l_lo, row=l_hi*4+r)

            // ---- in-wave 4x4 transpose within lane groups of 4 ----
            float t0, e0, e1, e2, e3, f0, f1, f2, f3;
            t0 = __shfl_xor(m[1], 1); e0 = (p4 & 1) ? t0 : m[0];
            t0 = __shfl_xor(m[0], 1); e1 = (p4 & 1) ? m[1] : t0;
            t0 = __shfl_xor(m[3], 1); e2 = (p4 & 1) ? t0 : m[2];
            t0 = __shfl_xor(m[2], 1); e3 = (p4 & 1) ? m[3] : t0;
            t0 = __shfl_xor(e2, 2); f0 = (p4 & 2) ? t0 : e0;
            t0 = __shfl_xor(e3, 2); f1 = (p4 & 2) ? t0 : e1;
            t0 = __shfl_xor(e0, 2); f2 = (p4 & 2) ? e2 : t0;
            t0 = __shfl_xor(e1, 2); f3 = (p4 & 2) ? e3 : t0;
            // lane now owns gates (i,f,g,o)=(f0,f1,f2,f3) of (row, uglob)

            float gi = f0 + xv * wx_i + bias_i;
            float gf = f1 + xv * wx_f + bias_f;
            float gg = f2 + xv * wx_g + bias_g;
            float go = f3 + xv * wx_o + bias_o;
            float iv = 1.f / (1.f + __expf(-gi));
            float fv = 1.f / (1.f + __expf(-gf));
            float gv = 2.f / (1.f + __expf(-2.f * gg)) - 1.f;
            float ov = 1.f / (1.f + __expf(-go));
            cst = fv * cst + iv * gv;
            float hv = ov * (2.f / (1.f + __expf(-2.f * cst)) - 1.f);

            // ---- publish: pair even/odd units, tagged dword, fire-forget ----
            unsigned hval;
            { union { f16 f; unsigned short s; } cv; cv.f = (f16)hv; hval = cv.s; }
            unsigned hodd = __shfl_xor(hval, 4);
            const unsigned wtag = (unsigned)(((t + 1) >> 2) & 1);
            if ((l_lo & 4) == 0) {
                unsigned dw = ((hval | (hodd << 16)) & ~1u) | wtag;
                f16* dst = hbuf + (size_t)((t + 1) & 3) * HBUF_ELEMS + st_idx;
                asm volatile("global_store_dword %0, %1, off sc0 sc1"
                             :: "v"(dst), "v"(dw) : "memory");
            }
        }

        // ---- readout in slack: designated wave computes y[bg*16+cg][t-1] ----
        if (t >= 1 && cg < 16 && ((t & 3) == w)) {
            float ry = 0.f;
            if (l_lo == cg) {
                const f16x8* wv8 = (const f16x8*)wlsh;
#pragma unroll
                for (int j = 0; j < 16; ++j) {
                    f16x8 wl8 = wv8[j * 4 + l_hi];
#pragma unroll
                    for (int e = 0; e < 8; ++e)
                        ry += (float)af[j][e] * (float)wl8[e];
                }
            }
            ry += __shfl_xor(ry, 16);
            ry += __shfl_xor(ry, 32);
            if (l_lo == cg && l_hi == 0)
                out[(bg * 16 + cg) * TT + (t - 1)] = blv + ry;
        }
    }
}

extern "C" void kernel_launch(void* const* d_in, const int* in_sizes, int n_in,
                              void* d_out, int out_size, void* d_ws, size_t ws_size,
                              hipStream_t stream) {
    const float* x  = (const float*)d_in[0];
    const float* Wx = (const float*)d_in[1];
    const float* Wh = (const float*)d_in[2];
    const float* bv = (const float*)d_in[3];
    const float* Wl = (const float*)d_in[4];
    const float* bl = (const float*)d_in[5];
    float* out = (float*)d_out;
    char* ws = (char*)d_ws;

    f16* wpack = (f16*)(ws + WPACK_OFF);
    f16* hbuf  = (f16*)(ws + HBUF_OFF);
    f16* wl16  = (f16*)(ws + WL16_OFF);

    init_kernel<<<512, 256, 0, stream>>>(Wl, wl16, (unsigned*)hbuf);
    pack_kernel<<<512, 256, 0, stream>>>(Wh, wpack);
    lstm_kernel<<<256, 256, 0, stream>>>(x, Wx, bv, bl, wpack, hbuf, wl16, out);
}

// Round 8
// 2209.343 us; speedup vs baseline: 7.4305x; 1.0619x over previous
//
#include <hip/hip_runtime.h>
#include <hip/hip_fp16.h>

// LSTM: B=128, T=1024, I=1, H=512, O=1
// R8: tag-in-payload protocol (R5-R7, proven). Changes:
//  - readout rotated over all 128 (cg,w) pairs, all-lane parallel dot2
//    (removes R7's 128-deep single-lane serial FMA straggler)
//  - own-quarter MFMA chain pre-barrier (slots reordered so bf[0..3] = own)
//  - x load hoisted above poll; out init dropped (single plain writer).

typedef _Float16 f16;
typedef _Float16 f16x2 __attribute__((ext_vector_type(2)));
typedef _Float16 f16x8 __attribute__((ext_vector_type(8)));
typedef float f32x4 __attribute__((ext_vector_type(4)));

#define BATCH 128
#define TT 1024
#define HID 512

#define WPACK_OFF   0
#define WPACK_BYTES (32*4*16*64*16)              // 2 MiB packed f16 Wh fragments
#define HBUF_OFF    (WPACK_OFF + WPACK_BYTES)
#define HBUF_ELEMS  (BATCH*HID)                  // 65536 f16 = 128 KiB per buffer
#define WL16_OFF    (HBUF_OFF + 4*HBUF_ELEMS*2)  // 512 f16 Wl

__global__ __launch_bounds__(256) void init_kernel(const float* Wl, f16* wl16,
                                                   unsigned* hbuf) {
    int idx = blockIdx.x * 256 + threadIdx.x;    // grid 512*256 = 131072
    // 4 h buffers = 131072 dwords. buf0 = zeros (h_0, tag 0);
    // bufs 1..3 = 0x00010001 (dword bit0=1 -> stale for tag-0 readers)
    hbuf[idx] = ((idx >> 15) == 0) ? 0u : 0x00010001u;
    if (idx < HID) wl16[idx] = (f16)Wl[idx];
}

// Pack Wh (512 x 2048, row = source k, col = gate*512 + j) into per-(cg,wave)
// B-fragments, full k, wave's 16-col slice. SLOT ORDER: slot s holds physical
// k-tile jt = (wv*4 + s) & 15, so slots 0..3 are the wave's own poll quarter.
__global__ __launch_bounds__(256) void pack_kernel(const float* __restrict__ Wh,
                                                   f16* __restrict__ wpack) {
    int tid  = blockIdx.x * 256 + threadIdx.x;   // 131072 = 32cg*4wv*16slot*64lane
    int lane = tid & 63;
    int s    = (tid >> 6) & 15;
    int wv   = (tid >> 10) & 3;
    int cg   = tid >> 12;
    int l_lo = lane & 15, l_hi = lane >> 4;
    int jt = ((wv * 4) + s) & 15;                // physical k-tile
    int jj = l_lo >> 2, q = l_lo & 3;
    int c = q * 512 + cg * 16 + wv * 4 + jj;
    int kbase = jt * 32 + l_hi * 8;
    f16x8 v;
#pragma unroll
    for (int e = 0; e < 8; ++e) v[e] = (f16)Wh[(kbase + e) * 2048 + c];
    ((f16x8*)wpack)[tid] = v;
}

__device__ __forceinline__ float dot8(f16x8 a, f16x8 b, float acc) {
#if __has_builtin(__builtin_amdgcn_fdot2)
    acc = __builtin_amdgcn_fdot2(__builtin_shufflevector(a, a, 0, 1),
                                 __builtin_shufflevector(b, b, 0, 1), acc, false);
    acc = __builtin_amdgcn_fdot2(__builtin_shufflevector(a, a, 2, 3),
                                 __builtin_shufflevector(b, b, 2, 3), acc, false);
    acc = __builtin_amdgcn_fdot2(__builtin_shufflevector(a, a, 4, 5),
                                 __builtin_shufflevector(b, b, 4, 5), acc, false);
    acc = __builtin_amdgcn_fdot2(__builtin_shufflevector(a, a, 6, 7),
                                 __builtin_shufflevector(b, b, 6, 7), acc, false);
#else
#pragma unroll
    for (int e = 0; e < 8; ++e) acc += (float)a[e] * (float)b[e];
#endif
    return acc;
}

__global__ __launch_bounds__(256, 1) void lstm_kernel(
    const float* __restrict__ x, const float* __restrict__ Wx,
    const float* __restrict__ bvec, const float* __restrict__ blp,
    const f16* __restrict__ wpack, f16* __restrict__ hbuf,
    const f16* __restrict__ wl16, float* __restrict__ out)
{
    const int tid = threadIdx.x;
    const int cg = blockIdx.x >> 3;      // hidden-group 0..31
    const int bg = blockIdx.x & 7;       // batch-group 0..7
    const int w = tid >> 6, lane = tid & 63;
    const int l_lo = lane & 15, l_hi = lane >> 4;

    __shared__ f16 hsh[2][8192];         // [row16][k512], XOR-swizzled, dbuf
    __shared__ f16 wlsh[512];

    if (tid < 64)                         // Wl -> LDS once
        *(f16x8*)(wlsh + tid * 8) = *(const f16x8*)(wl16 + tid * 8);

    // ---- persistent B fragments: slot s = physical tile (w*4+s)&15 ----
    f16x8 bf[16];
    {
        const f16x8* wp = (const f16x8*)wpack + (size_t)((cg * 4 + w) * 16) * 64 + lane;
#pragma unroll
        for (int s = 0; s < 16; ++s) bf[s] = wp[s * 64];
    }

    // ---- per-lane (row, unit) ownership after transpose ----
    const int row  = l_hi * 4 + (l_lo & 3);
    const int uglob = cg * 16 + w * 4 + (l_lo >> 2);
    const int bglob = bg * 16 + row;
    const float bias_i = bvec[0*512+uglob], bias_f = bvec[1*512+uglob];
    const float bias_g = bvec[2*512+uglob], bias_o = bvec[3*512+uglob];
    const float wx_i = Wx[0*512+uglob], wx_f = Wx[1*512+uglob];
    const float wx_g = Wx[2*512+uglob], wx_o = Wx[3*512+uglob];
    const float blv = blp[0];

    // poll: lane covers row l_lo, k in wave w's quarter
    const int rd_base = bg * 8192 + ((w * 16 + l_hi) * 16 + l_lo) * 8;
    // publish (even-unit lanes): chunk [kblock=uglob>>3][row][f16 uglob&7]
    const int st_idx = bg * 8192 + ((uglob >> 3) * 16 + row) * 8 + (uglob & 7);

    const int p4 = l_lo & 3;             // in-group transpose id
    const int sx = (l_lo & 7) << 4;      // LDS XOR swizzle
    const int lbase = l_lo * 1024;       // LDS row byte base
    const int base_ws = w * 256 + l_hi * 16;  // in-row byte off of slot 0
    const int xrow = bglob * TT;

    float cst = 0.f;

    for (int t = 0; t <= TT; ++t) {
        const f16* hp = hbuf + (size_t)(t & 3) * HBUF_ELEMS + rd_base;
        const unsigned expect = (unsigned)((t >> 2) & 1);
        float xv = x[xrow + (t < TT ? t : 0)];   // hoisted; arrives under poll

        // ---- poll the data itself: all 16 dword tags must be fresh ----
        f16x8 s0, s1, s2, s3;
        for (;;) {
            asm volatile(
                "global_load_dwordx4 %0, %4, off sc0 sc1\n\t"
                "global_load_dwordx4 %1, %5, off sc0 sc1\n\t"
                "global_load_dwordx4 %2, %6, off sc0 sc1\n\t"
                "global_load_dwordx4 %3, %7, off sc0 sc1\n\t"
                "s_waitcnt vmcnt(0)"
                : "=&v"(s0), "=&v"(s1), "=&v"(s2), "=&v"(s3)
                : "v"(hp), "v"(hp + 512), "v"(hp + 1024), "v"(hp + 1536)
                : "memory");
            union { f16x8 v; unsigned u[4]; } a0, a1, a2, a3;
            a0.v = s0; a1.v = s1; a2.v = s2; a3.v = s3;
            unsigned bad =
                ((a0.u[0] ^ expect) | (a0.u[1] ^ expect) |
                 (a0.u[2] ^ expect) | (a0.u[3] ^ expect) |
                 (a1.u[0] ^ expect) | (a1.u[1] ^ expect) |
                 (a1.u[2] ^ expect) | (a1.u[3] ^ expect) |
                 (a2.u[0] ^ expect) | (a2.u[1] ^ expect) |
                 (a2.u[2] ^ expect) | (a2.u[3] ^ expect) |
                 (a3.u[0] ^ expect) | (a3.u[1] ^ expect) |
                 (a3.u[2] ^ expect) | (a3.u[3] ^ expect)) & 1u;
            if (__all(bad == 0u)) break;
        }
        __builtin_amdgcn_sched_barrier(0);

        // ---- stage wave's k-quarter into shared h tile (swizzled) ----
        char* hb = (char*)hsh[t & 1];
        const int wb = lbase + base_ws;
        *(f16x8*)(hb + ((wb +   0) ^ sx)) = s0;
        *(f16x8*)(hb + ((wb +  64) ^ sx)) = s1;
        *(f16x8*)(hb + ((wb + 128) ^ sx)) = s2;
        *(f16x8*)(hb + ((wb + 192) ^ sx)) = s3;

        // ---- own-quarter MFMA chain BEFORE the barrier (overlaps staging) ----
        f32x4 c0 = {0,0,0,0};
        if (t < TT) {
            c0 = __builtin_amdgcn_mfma_f32_16x16x32_f16(s0, bf[0], c0, 0,0,0);
            c0 = __builtin_amdgcn_mfma_f32_16x16x32_f16(s1, bf[1], c0, 0,0,0);
            c0 = __builtin_amdgcn_mfma_f32_16x16x32_f16(s2, bf[2], c0, 0,0,0);
            c0 = __builtin_amdgcn_mfma_f32_16x16x32_f16(s3, bf[3], c0, 0,0,0);
        }
        __syncthreads();

        if (t < TT) {
            // ---- remaining 12 slots from LDS, 3 independent chains ----
            f32x4 c1 = {0,0,0,0}, c2 = {0,0,0,0}, c3 = {0,0,0,0};
#pragma unroll
            for (int i = 0; i < 4; ++i) {
                f16x8 a1 = *(const f16x8*)(hb + ((lbase + ((base_ws + (4+i)*64) & 1023)) ^ sx));
                f16x8 a2 = *(const f16x8*)(hb + ((lbase + ((base_ws + (8+i)*64) & 1023)) ^ sx));
                f16x8 a3 = *(const f16x8*)(hb + ((lbase + ((base_ws + (12+i)*64) & 1023)) ^ sx));
                c1 = __builtin_amdgcn_mfma_f32_16x16x32_f16(a1, bf[ 4+i], c1, 0,0,0);
                c2 = __builtin_amdgcn_mfma_f32_16x16x32_f16(a2, bf[ 8+i], c2, 0,0,0);
                c3 = __builtin_amdgcn_mfma_f32_16x16x32_f16(a3, bf[12+i], c3, 0,0,0);
            }
            f32x4 m = (c0 + c1) + (c2 + c3);
            // m[r] = gates(pcol=l_lo, row=l_hi*4+r)

            // ---- in-wave 4x4 transpose within lane groups of 4 ----
            float t0, e0, e1, e2, e3, f0, f1, f2, f3;
            t0 = __shfl_xor(m[1], 1); e0 = (p4 & 1) ? t0 : m[0];
            t0 = __shfl_xor(m[0], 1); e1 = (p4 & 1) ? m[1] : t0;
            t0 = __shfl_xor(m[3], 1); e2 = (p4 & 1) ? t0 : m[2];
            t0 = __shfl_xor(m[2], 1); e3 = (p4 & 1) ? m[3] : t0;
            t0 = __shfl_xor(e2, 2); f0 = (p4 & 2) ? t0 : e0;
            t0 = __shfl_xor(e3, 2); f1 = (p4 & 2) ? t0 : e1;
            t0 = __shfl_xor(e0, 2); f2 = (p4 & 2) ? e2 : t0;
            t0 = __shfl_xor(e1, 2); f3 = (p4 & 2) ? e3 : t0;
            // lane owns gates (i,f,g,o)=(f0,f1,f2,f3) of (row, uglob)

            float gi = f0 + xv * wx_i + bias_i;
            float gf = f1 + xv * wx_f + bias_f;
            float gg = f2 + xv * wx_g + bias_g;
            float go = f3 + xv * wx_o + bias_o;
            float iv = 1.f / (1.f + __expf(-gi));
            float fv = 1.f / (1.f + __expf(-gf));
            float gv = 2.f / (1.f + __expf(-2.f * gg)) - 1.f;
            float ov = 1.f / (1.f + __expf(-go));
            cst = fv * cst + iv * gv;
            float hv = ov * (2.f / (1.f + __expf(-2.f * cst)) - 1.f);

            // ---- publish: pair even/odd units, tagged dword, fire-forget ----
            unsigned hval;
            { union { f16 f; unsigned short s; } cv; cv.f = (f16)hv; hval = cv.s; }
            unsigned hodd = __shfl_xor(hval, 4);
            const unsigned wtag = (unsigned)(((t + 1) >> 2) & 1);
            if ((l_lo & 4) == 0) {
                unsigned dw = ((hval | (hodd << 16)) & ~1u) | wtag;
                f16* dst = hbuf + (size_t)((t + 1) & 3) * HBUF_ELEMS + st_idx;
                asm volatile("global_store_dword %0, %1, off sc0 sc1"
                             :: "v"(dst), "v"(dw) : "memory");
            }
        }

        // ---- readout y[.,t-1]: rotates over all 128 (cg,w); all lanes ----
        if (t >= 1 && cg == ((t >> 2) & 31) && w == (t & 3)) {
            float r0 = 0.f, r1 = 0.f, r2 = 0.f, r3 = 0.f;
            // own slots 0..3 from regs
            r0 = dot8(s0, *(const f16x8*)(wlsh + (((base_ws + 0*64) & 1023) >> 1)), r0);
            r1 = dot8(s1, *(const f16x8*)(wlsh + (((base_ws + 1*64) & 1023) >> 1)), r1);
            r2 = dot8(s2, *(const f16x8*)(wlsh + (((base_ws + 2*64) & 1023) >> 1)), r2);
            r3 = dot8(s3, *(const f16x8*)(wlsh + (((base_ws + 3*64) & 1023) >> 1)), r3);
            // slots 4..15 from LDS
#pragma unroll
            for (int i = 0; i < 4; ++i) {
                f16x8 a1 = *(const f16x8*)(hb + ((lbase + ((base_ws + (4+i)*64) & 1023)) ^ sx));
                f16x8 a2 = *(const f16x8*)(hb + ((lbase + ((base_ws + (8+i)*64) & 1023)) ^ sx));
                f16x8 a3 = *(const f16x8*)(hb + ((lbase + ((base_ws + (12+i)*64) & 1023)) ^ sx));
                r0 = dot8(a1, *(const f16x8*)(wlsh + (((base_ws + (4+i)*64) & 1023) >> 1)), r0);
                r1 = dot8(a2, *(const f16x8*)(wlsh + (((base_ws + (8+i)*64) & 1023) >> 1)), r1);
                r2 = dot8(a3, *(const f16x8*)(wlsh + (((base_ws + (12+i)*64) & 1023) >> 1)), r2);
            }
            float ry = (r0 + r1) + (r2 + r3);
            ry += __shfl_xor(ry, 16);
            ry += __shfl_xor(ry, 32);
            if (lane < 16)               // l_hi == 0 holds row l_lo's sum
                out[(bg * 16 + l_lo) * TT + (t - 1)] = blv + ry;
        }
    }
}

extern "C" void kernel_launch(void* const* d_in, const int* in_sizes, int n_in,
                              void* d_out, int out_size, void* d_ws, size_t ws_size,
                              hipStream_t stream) {
    const float* x  = (const float*)d_in[0];
    const float* Wx = (const float*)d_in[1];
    const float* Wh = (const float*)d_in[2];
    const float* bv = (const float*)d_in[3];
    const float* Wl = (const float*)d_in[4];
    const float* bl = (const float*)d_in[5];
    float* out = (float*)d_out;
    char* ws = (char*)d_ws;

    f16* wpack = (f16*)(ws + WPACK_OFF);
    f16* hbuf  = (f16*)(ws + HBUF_OFF);
    f16* wl16  = (f16*)(ws + WL16_OFF);

    init_kernel<<<512, 256, 0, stream>>>(Wl, wl16, (unsigned*)hbuf);
    pack_kernel<<<512, 256, 0, stream>>>(Wh, wpack);
    lstm_kernel<<<256, 256, 0, stream>>>(x, Wx, bv, bl, wpack, hbuf, wl16, out);
}